// Round 3
// baseline (662.261 us; speedup 1.0000x reference)
//
#include <hip/hip_runtime.h>
#include <cstdint>
#include <cstddef>

#define DEV __device__ __forceinline__

typedef __attribute__((ext_vector_type(8))) short short8;
typedef __attribute__((ext_vector_type(4))) float f32x4;
typedef __attribute__((ext_vector_type(4))) unsigned short ushort4v;

DEV unsigned short f2bf(float f){
  union { float f; unsigned int i; } v; v.f = f;
  unsigned int r = v.i + 0x7fffu + ((v.i >> 16) & 1u);
  return (unsigned short)(r >> 16);
}

DEV void gld_lds16(const unsigned short* g, unsigned short* lds){
  __builtin_amdgcn_global_load_lds((const __attribute__((address_space(1))) void*)g,
                                   (__attribute__((address_space(3))) void*)lds, 16, 0, 0);
}

// =================== 256x256 8-wave deep-pipelined GEMM (T2+T3+T4+T5) ===================
// C[M,N] = A[M,K] @ Bt[N,K]^T + bias.  BK=64, 4 phases/K-tile, counted vmcnt(4).
// LDS per buf: A[256][64] rows linear; B phys row r = nh*128 + wc*32 + j <-> global row
// nb + wc*64 + nh*32 + j.  Slot swizzle: phys_slot = logical_slot ^ (row&7) (8x16B slots).
// Staged via pre-swizzled GLOBAL source col + linear LDS dest (rule #21).
// Region deadness (quadrant order (mh,nh) = (0,0),(1,0),(0,1),(1,1)):
//   B-nh0 dead after ph1 -> staged ph2 (tile u+2); A-mh0 (chunks 0,2) dead after ph2 -> ph3;
//   B-nh1 dead after ph3 -> staged next-tile ph0 (tile u+1); A-mh1 (1,3) -> next ph1.
// vmcnt(4) at each tile end leaves exactly ph2+ph3's 4 issues outstanding.
template<int EPI>
__global__ __launch_bounds__(512, 2)
void gemm256(const unsigned short* __restrict__ A,
             const unsigned short* __restrict__ Bt,
             const float* __restrict__ bias,
             void* __restrict__ C, int M, int N, int K)
{
  __shared__ __align__(16) unsigned short lds[65536];   // 128 KiB: [buf][A|B][...]

  const int tid = threadIdx.x, wid = tid >> 6, l = tid & 63;
  const int wr = wid >> 2, wc = wid & 3;

  const int nbm = M / 256, nbn = N / 256;
  const int nwg = nbm * nbn;
  const int q8 = nwg >> 3, r8 = nwg & 7;
  const int xcd = blockIdx.x & 7, within = blockIdx.x >> 3;
  const int wg = (xcd < r8 ? xcd * (q8 + 1) : r8 * (q8 + 1) + (xcd - r8) * q8) + within;
  const int mb = (wg % nbm) * 256, nb = (wg / nbm) * 256;

  const int nk = K / 64;

  // staging thread constants
  const int srow8 = tid >> 3;                             // 0..63 row within chunk
  const int sslot = (tid & 7) ^ ((tid >> 3) & 7);         // logical slot loaded into phys slot tid&7

  // read-side lane constants
  const int rl = l & 15, kslot = l >> 4, sx = l & 7;
  const int so0 = ((kslot) ^ sx) * 8;                     // ks=0 slot byte-offset (in shorts)
  const int so1 = ((4 + kslot) ^ sx) * 8;                 // ks=1
  const int arowb = wr * 128 + rl;
  const int bline = wc * 32 + rl;

  f32x4 acc[8][4];
  #pragma unroll
  for (int m = 0; m < 8; m++)
    #pragma unroll
    for (int n = 0; n < 4; n++) acc[m][n] = (f32x4){0.f, 0.f, 0.f, 0.f};

#define STAGE_A(c, tt, pp) \
  gld_lds16(A + (size_t)(mb + (c)*64 + srow8) * K + (size_t)(tt)*64 + sslot*8, \
            lds + (pp)*32768 + (c)*4096 + tid*8)
#define STAGE_B(c, tt, pp) \
  gld_lds16(Bt + (size_t)(nb + (((c)*2 + (srow8>>5)) & 3)*64 + ((c)>>1)*32 + (srow8&31)) * K \
                 + (size_t)(tt)*64 + sslot*8, \
            lds + (pp)*32768 + 16384 + (c)*4096 + tid*8)

#define PHASE(mh, nh, STAGES, TAIL) do { \
    short8 af[4][2], bf[2][2]; \
    _Pragma("unroll") \
    for (int i = 0; i < 4; i++){ \
      const unsigned short* ap = lds + pof + (arowb + (mh)*64 + i*16) * 64; \
      af[i][0] = *(const short8*)(ap + so0); \
      af[i][1] = *(const short8*)(ap + so1); \
    } \
    _Pragma("unroll") \
    for (int j = 0; j < 2; j++){ \
      const unsigned short* bp = lds + pof + 16384 + ((nh)*128 + bline + j*16) * 64; \
      bf[j][0] = *(const short8*)(bp + so0); \
      bf[j][1] = *(const short8*)(bp + so1); \
    } \
    STAGES; \
    asm volatile("" ::: "memory"); \
    __builtin_amdgcn_s_barrier(); \
    asm volatile("s_waitcnt lgkmcnt(0)" ::: "memory"); \
    __builtin_amdgcn_s_setprio(1); \
    _Pragma("unroll") \
    for (int i = 0; i < 4; i++) \
      _Pragma("unroll") \
      for (int j = 0; j < 2; j++){ \
        acc[(mh)*4+i][(nh)*2+j] = __builtin_amdgcn_mfma_f32_16x16x32_bf16(af[i][0], bf[j][0], acc[(mh)*4+i][(nh)*2+j], 0, 0, 0); \
        acc[(mh)*4+i][(nh)*2+j] = __builtin_amdgcn_mfma_f32_16x16x32_bf16(af[i][1], bf[j][1], acc[(mh)*4+i][(nh)*2+j], 0, 0, 0); \
      } \
    __builtin_amdgcn_s_setprio(0); \
    TAIL; \
    asm volatile("" ::: "memory"); \
    __builtin_amdgcn_s_barrier(); \
  } while(0)

  // prologue: tile0 full -> buf0; tile1 chunks B0,B1,A0,A2 -> buf1
  STAGE_A(0, 0, 0); STAGE_A(1, 0, 0); STAGE_A(2, 0, 0); STAGE_A(3, 0, 0);
  STAGE_B(0, 0, 0); STAGE_B(1, 0, 0); STAGE_B(2, 0, 0); STAGE_B(3, 0, 0);
  if (nk > 1){ STAGE_B(0, 1, 1); STAGE_B(1, 1, 1); STAGE_A(0, 1, 1); STAGE_A(2, 1, 1); }
  if (nk > 1) asm volatile("s_waitcnt vmcnt(4)" ::: "memory");
  else        asm volatile("s_waitcnt vmcnt(0)" ::: "memory");
  asm volatile("" ::: "memory");
  __builtin_amdgcn_s_barrier();

  int pcur = 0;
  for (int u = 0; u < nk; u++){
    const int pof = pcur * 32768;
    const int pnx = pcur ^ 1;
    const bool s1 = (u + 1 < nk), s2 = (u + 2 < nk);
    PHASE(0, 0, { if (s1){ STAGE_B(2, u + 1, pnx); STAGE_B(3, u + 1, pnx); } }, {});
    PHASE(1, 0, { if (s1){ STAGE_A(1, u + 1, pnx); STAGE_A(3, u + 1, pnx); } }, {});
    PHASE(0, 1, { if (s2){ STAGE_B(0, u + 2, pcur); STAGE_B(1, u + 2, pcur); } }, {});
    PHASE(1, 1, { if (s2){ STAGE_A(0, u + 2, pcur); STAGE_A(2, u + 2, pcur); } },
          { if (u == nk - 2)     asm volatile("s_waitcnt vmcnt(0)" ::: "memory");
            else if (u < nk - 2) asm volatile("s_waitcnt vmcnt(4)" ::: "memory"); });
    pcur ^= 1;
  }
#undef PHASE
#undef STAGE_A
#undef STAGE_B

  // epilogue
  #pragma unroll
  for (int n = 0; n < 4; n++){
    const int col = nb + wc * 64 + n * 16 + rl;
    const float bv = bias ? bias[col] : 0.f;
    #pragma unroll
    for (int m = 0; m < 8; m++){
      const int row0 = mb + wr * 128 + m * 16 + (kslot << 2);
      #pragma unroll
      for (int jj = 0; jj < 4; jj++){
        float v = acc[m][n][jj] + bv;
        size_t idx = (size_t)(row0 + jj) * N + col;
        if (EPI == 0)       ((float*)C)[idx] = v;
        else if (EPI == 3)  __builtin_nontemporal_store(v, &((float*)C)[idx]);
        else if (EPI == 1)  ((unsigned short*)C)[idx] = f2bf(v);
        else { v = v > 0.f ? v : 0.f; ((unsigned short*)C)[idx] = f2bf(v); }
      }
    }
  }
}

// ---------------- GEMM (m97-style 2-phase): C[M,N] = A@Bt^T + bias ----------------
template<int BM, int BN, int EPI>
__global__ __launch_bounds__(256, 2)
void gemm_bt(const unsigned short* __restrict__ A,
             const unsigned short* __restrict__ Bt,
             const float* __restrict__ bias,
             void* __restrict__ C, int M, int N, int K)
{
  constexpr int MF = BM / 32, NF = BN / 32;
  constexpr int LA = BM / 64, LB = BN / 64;
  __shared__ __align__(16) unsigned short lds[2 * (BM + BN) * 32];

  const int tid = threadIdx.x, w = tid >> 6, l = tid & 63;
  const int wr = w >> 1, wc = w & 1;

  const int nbm = M / BM, nbn = N / BN;
  const int nwg = nbm * nbn;
  const int q8 = nwg >> 3, r8 = nwg & 7;
  const int xcd = blockIdx.x & 7, within = blockIdx.x >> 3;
  const int wg = (xcd < r8 ? xcd * (q8 + 1) : r8 * (q8 + 1) + (xcd - r8) * q8) + within;
  const int mb = (wg % nbm) * BM, nb = (wg / nbm) * BN;

  unsigned short* As0 = lds;
  unsigned short* Bs0 = lds + BM * 32;
  unsigned short* As1 = lds + (BM + BN) * 32;
  unsigned short* Bs1 = As1 + BM * 32;

  f32x4 acc[MF][NF];
  #pragma unroll
  for (int m = 0; m < MF; m++)
    #pragma unroll
    for (int n = 0; n < NF; n++) acc[m][n] = (f32x4){0.f, 0.f, 0.f, 0.f};

  const int srow = l >> 2;
  const int scol = (((l & 3) ^ ((l >> 2) & 3) ^ ((l >> 4) & 3)) * 8);
  const int rswz = (l & 3) ^ ((l >> 2) & 3);

  #define STAGE(Ad, Bd, k0) do { \
    _Pragma("unroll") \
    for (int i = 0; i < LA; i++){ \
      int chunk = i * 4 + w; \
      gld_lds16(A + (size_t)(mb + chunk * 16 + srow) * K + (k0) + scol, (Ad) + chunk * 512); \
    } \
    _Pragma("unroll") \
    for (int i = 0; i < LB; i++){ \
      int chunk = i * 4 + w; \
      gld_lds16(Bt + (size_t)(nb + chunk * 16 + srow) * K + (k0) + scol, (Bd) + chunk * 512); \
    } } while(0)

  STAGE(As0, Bs0, 0);
  const int nk = K / 32;
  const int rdoff = ((l >> 4) ^ rswz) * 8;
  for (int kt = 0; kt < nk; kt++){
    __syncthreads();
    unsigned short* Ac = (kt & 1) ? As1 : As0;
    unsigned short* Bc = (kt & 1) ? Bs1 : Bs0;
    if (kt + 1 < nk){
      unsigned short* An = (kt & 1) ? As0 : As1;
      unsigned short* Bn = (kt & 1) ? Bs0 : Bs1;
      STAGE(An, Bn, (kt + 1) * 32);
    }
    short8 af[MF], bfr[NF];
    #pragma unroll
    for (int m = 0; m < MF; m++)
      af[m] = *(const short8*)(Ac + (wr * (BM / 2) + m * 16 + (l & 15)) * 32 + rdoff);
    #pragma unroll
    for (int n = 0; n < NF; n++)
      bfr[n] = *(const short8*)(Bc + (wc * (BN / 2) + n * 16 + (l & 15)) * 32 + rdoff);
    #pragma unroll
    for (int m = 0; m < MF; m++)
      #pragma unroll
      for (int n = 0; n < NF; n++)
        acc[m][n] = __builtin_amdgcn_mfma_f32_16x16x32_bf16(af[m], bfr[n], acc[m][n], 0, 0, 0);
  }
  #undef STAGE

  #pragma unroll
  for (int n = 0; n < NF; n++){
    const int col = nb + wc * (BN / 2) + n * 16 + (l & 15);
    const float bv = bias ? bias[col] : 0.f;
    #pragma unroll
    for (int m = 0; m < MF; m++){
      const int row0 = mb + wr * (BM / 2) + m * 16 + ((l >> 4) << 2);
      #pragma unroll
      for (int jj = 0; jj < 4; jj++){
        float v = acc[m][n][jj] + bv;
        size_t idx = (size_t)(row0 + jj) * N + col;
        if (EPI == 0)       ((float*)C)[idx] = v;
        else if (EPI == 3)  __builtin_nontemporal_store(v, &((float*)C)[idx]);
        else if (EPI == 1)  ((unsigned short*)C)[idx] = f2bf(v);
        else { v = v > 0.f ? v : 0.f; ((unsigned short*)C)[idx] = f2bf(v); }
      }
    }
  }
}

// ---------------- Flash attention: 64 q-rows / block (4 waves x 16), dh=64, H=16 ----------------
template<int CAUSAL>
__global__ __launch_bounds__(256)
void attn_kernel(const unsigned short* __restrict__ Qb, int ldq,
                 const unsigned short* __restrict__ Kb, int ldk,
                 const unsigned short* __restrict__ Vb, int ldv,
                 unsigned short* __restrict__ Ob, int ldo)
{
  constexpr int S = 1024;
  __shared__ __align__(16) unsigned short vt[64][40];
  __shared__ __align__(16) unsigned short plds[4][16][40];
  const int tid = threadIdx.x, w = tid >> 6, l = tid & 63;
  const int qt = blockIdx.x, bh = blockIdx.y;
  const int b = bh >> 4, h = bh & 15;
  const int hoff = h * 64;
  const size_t rb = (size_t)b * S;

  const int qrow = qt * 64 + w * 16 + (l & 15);
  const unsigned short* qp = Qb + (rb + qrow) * ldq + hoff + ((l >> 4) * 8);
  short8 qf0 = *(const short8*)qp;
  short8 qf1 = *(const short8*)(qp + 32);

  float m_run[4] = {-1e30f, -1e30f, -1e30f, -1e30f};
  float l_run[4] = {0.f, 0.f, 0.f, 0.f};
  f32x4 oacc[4];
  #pragma unroll
  for (int t = 0; t < 4; t++) oacc[t] = (f32x4){0.f, 0.f, 0.f, 0.f};

  const int qmax = qt * 64 + w * 16 + 15;
  const int nkeys = CAUSAL ? (qt * 64 + 64) : S;
  const int skey = tid >> 3, sd8 = (tid & 7) * 8;

  for (int kb = 0; kb < nkeys; kb += 32){
    short8 vv = *(const short8*)(Vb + (rb + kb + skey) * ldv + hoff + sd8);
    #pragma unroll
    for (int i = 0; i < 8; i++) vt[sd8 + i][skey] = (unsigned short)vv[i];
    __syncthreads();
    if (!CAUSAL || kb <= qmax){
      f32x4 sc[2];
      #pragma unroll
      for (int g = 0; g < 2; g++){
        const unsigned short* kp = Kb + (rb + kb + g * 16 + (l & 15)) * ldk + hoff + ((l >> 4) * 8);
        short8 kf0 = *(const short8*)kp;
        short8 kf1 = *(const short8*)(kp + 32);
        f32x4 z = (f32x4){0.f, 0.f, 0.f, 0.f};
        z = __builtin_amdgcn_mfma_f32_16x16x32_bf16(qf0, kf0, z, 0, 0, 0);
        z = __builtin_amdgcn_mfma_f32_16x16x32_bf16(qf1, kf1, z, 0, 0, 0);
        sc[g] = z;
      }
      #pragma unroll
      for (int jj = 0; jj < 4; jj++){
        float s0 = sc[0][jj] * 0.125f, s1 = sc[1][jj] * 0.125f;
        if (CAUSAL){
          int q = qt * 64 + w * 16 + ((l >> 4) << 2) + jj;
          if (kb + (l & 15) > q)      s0 = -1e30f;
          if (kb + 16 + (l & 15) > q) s1 = -1e30f;
        }
        float mx = fmaxf(s0, s1);
        mx = fmaxf(mx, __shfl_xor(mx, 1));
        mx = fmaxf(mx, __shfl_xor(mx, 2));
        mx = fmaxf(mx, __shfl_xor(mx, 4));
        mx = fmaxf(mx, __shfl_xor(mx, 8));
        float mnew = fmaxf(m_run[jj], mx);
        float scal = __expf(m_run[jj] - mnew);
        m_run[jj] = mnew;
        float p0 = __expf(s0 - mnew), p1 = __expf(s1 - mnew);
        float rs = p0 + p1;
        rs += __shfl_xor(rs, 1); rs += __shfl_xor(rs, 2);
        rs += __shfl_xor(rs, 4); rs += __shfl_xor(rs, 8);
        l_run[jj] = l_run[jj] * scal + rs;
        #pragma unroll
        for (int t = 0; t < 4; t++) oacc[t][jj] *= scal;
        int qr = ((l >> 4) << 2) + jj;
        plds[w][qr][l & 15]      = f2bf(p0);
        plds[w][qr][16 + (l & 15)] = f2bf(p1);
      }
      asm volatile("s_waitcnt lgkmcnt(0)" ::: "memory");
      short8 pf = *(const short8*)&plds[w][l & 15][(l >> 4) * 8];
      #pragma unroll
      for (int t = 0; t < 4; t++){
        short8 vf = *(const short8*)&vt[t * 16 + (l & 15)][(l >> 4) * 8];
        oacc[t] = __builtin_amdgcn_mfma_f32_16x16x32_bf16(pf, vf, oacc[t], 0, 0, 0);
      }
    }
    __syncthreads();
  }
  #pragma unroll
  for (int jj = 0; jj < 4; jj++){
    float inv = 1.f / l_run[jj];
    int q = qt * 64 + w * 16 + ((l >> 4) << 2) + jj;
    #pragma unroll
    for (int t = 0; t < 4; t++)
      Ob[(rb + q) * ldo + hoff + t * 16 + (l & 15)] = f2bf(oacc[t][jj] * inv);
  }
}

// ---------------- LayerNorm over D=1024 ----------------
__global__ __launch_bounds__(256)
void ln_kernel(const float* __restrict__ x1, const float* __restrict__ x2,
               const float* __restrict__ g, const float* __restrict__ be,
               float* __restrict__ outf, unsigned short* __restrict__ outb)
{
  const int row = blockIdx.x, t = threadIdx.x;
  __shared__ float red[4];
  const float4 v1 = ((const float4*)(x1 + (size_t)row * 1024))[t];
  const float4 v2 = ((const float4*)(x2 + (size_t)row * 1024))[t];
  float x[4] = {v1.x + v2.x, v1.y + v2.y, v1.z + v2.z, v1.w + v2.w};
  float s = x[0] + x[1] + x[2] + x[3];
  for (int o = 1; o < 64; o <<= 1) s += __shfl_xor(s, o);
  const int w = t >> 6, l = t & 63;
  if (l == 0) red[w] = s;
  __syncthreads();
  const float mean = (red[0] + red[1] + red[2] + red[3]) * (1.f / 1024.f);
  float d[4]; float sq = 0.f;
  #pragma unroll
  for (int i = 0; i < 4; i++){ d[i] = x[i] - mean; sq += d[i] * d[i]; }
  __syncthreads();
  for (int o = 1; o < 64; o <<= 1) sq += __shfl_xor(sq, o);
  if (l == 0) red[w] = sq;
  __syncthreads();
  const float var = (red[0] + red[1] + red[2] + red[3]) * (1.f / 1024.f);
  const float inv = rsqrtf(var + 1e-5f);
  const int base = t * 4;
  #pragma unroll
  for (int i = 0; i < 4; i++){
    float o = d[i] * inv * g[base + i] + be[base + i];
    if (outf) outf[(size_t)row * 1024 + base + i] = o;
    outb[(size_t)row * 1024 + base + i] = f2bf(o);
  }
}

// ---------------- x0 = dec + positional encoding ----------------
__global__ __launch_bounds__(256)
void build_x0(const float* __restrict__ dec, float* __restrict__ xf, unsigned short* __restrict__ xb)
{
  const int i = blockIdx.x * 256 + threadIdx.x;
  const int i4 = i * 4;
  const int d0 = i4 & 1023;
  const int s  = (i4 >> 10) & 1023;
  float4 dv = ((const float4*)dec)[i];
  const float* dvp = (const float*)&dv;
  float o[4];
  #pragma unroll
  for (int j = 0; j < 4; j++){
    int dd = d0 + j;
    float e = (float)(dd & ~1) * (1.f / 1024.f);
    float den = expf(e * 9.210340371976184f);
    float ang = (float)s / den;
    float pe = (dd & 1) ? cosf(ang) : sinf(ang);
    o[j] = dvp[j] + pe;
  }
  ((float4*)xf)[i] = make_float4(o[0], o[1], o[2], o[3]);
  ushort4v ob; ob[0] = f2bf(o[0]); ob[1] = f2bf(o[1]); ob[2] = f2bf(o[2]); ob[3] = f2bf(o[3]);
  ((ushort4v*)xb)[i] = ob;
}

__global__ __launch_bounds__(256)
void cvt_bf16_k(const float* __restrict__ in, unsigned short* __restrict__ out)
{
  const int i = blockIdx.x * 256 + threadIdx.x;
  float4 v = ((const float4*)in)[i];
  ushort4v o; o[0] = f2bf(v.x); o[1] = f2bf(v.y); o[2] = f2bf(v.z); o[3] = f2bf(v.w);
  ((ushort4v*)out)[i] = o;
}

// ---------------- transpose + convert ----------------
__global__ __launch_bounds__(256)
void transpose_cvt(const float* __restrict__ in, unsigned short* __restrict__ out, int R, int C)
{
  __shared__ float t[32][33];
  const int cb = blockIdx.x * 32, rbk = blockIdx.y * 32;
  const int tx = threadIdx.x & 31, ty = threadIdx.x >> 5;
  #pragma unroll
  for (int i = 0; i < 4; i++)
    t[ty + 8 * i][tx] = in[(size_t)(rbk + ty + 8 * i) * C + cb + tx];
  __syncthreads();
  #pragma unroll
  for (int i = 0; i < 4; i++){
    int c = ty + 8 * i;
    out[(size_t)(cb + c) * R + rbk + tx] = f2bf(t[tx][c]);
  }
}

struct TPtrs { const float* src[8]; unsigned short* dst[8]; };
__global__ __launch_bounds__(256)
void transpose_cvt8(TPtrs p)
{
  __shared__ float t[32][33];
  const float* __restrict__ in = p.src[blockIdx.z];
  unsigned short* __restrict__ out = p.dst[blockIdx.z];
  const int cb = blockIdx.x * 32, rbk = blockIdx.y * 32;
  const int tx = threadIdx.x & 31, ty = threadIdx.x >> 5;
  #pragma unroll
  for (int i = 0; i < 4; i++)
    t[ty + 8 * i][tx] = in[(size_t)(rbk + ty + 8 * i) * 1024 + cb + tx];
  __syncthreads();
  #pragma unroll
  for (int i = 0; i < 4; i++){
    int c = ty + 8 * i;
    out[(size_t)(cb + c) * 1024 + rbk + tx] = f2bf(t[tx][c]);
  }
}

__global__ __launch_bounds__(256)
void copy_biases(const float* sbq, const float* sbk, const float* sbv,
                 const float* cbk, const float* cbv,
                 float* bqkv, float* bkvc)
{
  const int i = blockIdx.x * 256 + threadIdx.x;
  const int seg = i >> 10, off = i & 1023;
  if (seg == 0)      bqkv[off] = sbq[off];
  else if (seg == 1) bqkv[1024 + off] = sbk[off];
  else if (seg == 2) bqkv[2048 + off] = sbv[off];
  else if (seg == 3) bkvc[off] = cbk[off];
  else               bkvc[1024 + off] = cbv[off];
}

extern "C" void kernel_launch(void* const* d_in, const int* in_sizes, int n_in,
                              void* d_out, int out_size, void* d_ws, size_t ws_size,
                              hipStream_t stream)
{
  constexpr int S = 1024, D = 1024, V = 32000, DF = 4096;
  constexpr int M = 2 * S;
  constexpr int DD = D * D;
  constexpr int l3 = 3;

  const float* dec  = (const float*)d_in[0];
  const float* enc  = (const float*)d_in[1];
  const float* sWq = (const float*)d_in[5]  + l3 * DD;
  const float* sWk = (const float*)d_in[6]  + l3 * DD;
  const float* sWv = (const float*)d_in[7]  + l3 * DD;
  const float* sWo = (const float*)d_in[8]  + l3 * DD;
  const float* cWq = (const float*)d_in[9]  + l3 * DD;
  const float* cWk = (const float*)d_in[10] + l3 * DD;
  const float* cWv = (const float*)d_in[11] + l3 * DD;
  const float* cWo = (const float*)d_in[12] + l3 * DD;
  const float* sbq = (const float*)d_in[13] + l3 * D;
  const float* sbk = (const float*)d_in[14] + l3 * D;
  const float* sbv = (const float*)d_in[15] + l3 * D;
  const float* sbo = (const float*)d_in[16] + l3 * D;
  const float* cbq = (const float*)d_in[17] + l3 * D;
  const float* cbk = (const float*)d_in[18] + l3 * D;
  const float* cbv = (const float*)d_in[19] + l3 * D;
  const float* cbo = (const float*)d_in[20] + l3 * D;
  const float* ln1g = (const float*)d_in[21] + l3 * D;
  const float* ln2g = (const float*)d_in[22] + l3 * D;
  const float* ln3g = (const float*)d_in[23] + l3 * D;
  const float* ln1b = (const float*)d_in[24] + l3 * D;
  const float* ln2b = (const float*)d_in[25] + l3 * D;
  const float* ln3b = (const float*)d_in[26] + l3 * D;
  const float* fW1 = (const float*)d_in[27] + (size_t)l3 * D * DF;
  const float* fb1 = (const float*)d_in[28] + l3 * DF;
  const float* fW2 = (const float*)d_in[29] + (size_t)l3 * DF * D;
  const float* fb2 = (const float*)d_in[30] + l3 * D;
  const float* Wout = (const float*)d_in[31];
  const float* bout = (const float*)d_in[32];
  float* out = (float*)d_out;

  uint8_t* wsp = (uint8_t*)d_ws;
  auto alloc = [&](size_t bytes) -> void* {
    void* p = wsp; wsp += (bytes + 255) & ~(size_t)255; return p;
  };
  float*          x0f  = (float*)alloc((size_t)M * D * 4);
  unsigned short* x0b  = (unsigned short*)alloc((size_t)M * D * 2);
  unsigned short* encb = (unsigned short*)alloc((size_t)M * D * 2);
  unsigned short* wqkv = (unsigned short*)alloc((size_t)3 * DD * 2);
  unsigned short* wos  = (unsigned short*)alloc((size_t)DD * 2);
  unsigned short* wqc  = (unsigned short*)alloc((size_t)DD * 2);
  unsigned short* wkvc = (unsigned short*)alloc((size_t)2 * DD * 2);
  unsigned short* woc  = (unsigned short*)alloc((size_t)DD * 2);
  unsigned short* wf1  = (unsigned short*)alloc((size_t)D * DF * 2);
  unsigned short* wf2  = (unsigned short*)alloc((size_t)D * DF * 2);
  unsigned short* wvo  = (unsigned short*)alloc((size_t)V * D * 2);
  float*          bqkv = (float*)alloc(3 * D * 4);
  float*          bkvc = (float*)alloc(2 * D * 4);
  unsigned short* qkv  = (unsigned short*)alloc((size_t)M * 3 * D * 2);
  unsigned short* attnb= (unsigned short*)alloc((size_t)M * D * 2);
  float*          oproj= (float*)alloc((size_t)M * D * 4);
  float*          a1f  = (float*)alloc((size_t)M * D * 4);
  unsigned short* a1b  = (unsigned short*)alloc((size_t)M * D * 2);
  unsigned short* qc   = (unsigned short*)alloc((size_t)M * D * 2);
  unsigned short* kvc  = (unsigned short*)alloc((size_t)M * 2 * D * 2);
  float*          a2f  = (float*)alloc((size_t)M * D * 4);
  unsigned short* a2b  = (unsigned short*)alloc((size_t)M * D * 2);
  unsigned short* ffh  = (unsigned short*)alloc((size_t)M * DF * 2);
  unsigned short* yb   = (unsigned short*)alloc((size_t)M * D * 2);

  build_x0<<<M * D / 4 / 256, 256, 0, stream>>>(dec, x0f, x0b);
  cvt_bf16_k<<<M * D / 4 / 256, 256, 0, stream>>>(enc, encb);

  TPtrs tp;
  tp.src[0] = sWq; tp.dst[0] = wqkv;
  tp.src[1] = sWk; tp.dst[1] = wqkv + DD;
  tp.src[2] = sWv; tp.dst[2] = wqkv + 2 * DD;
  tp.src[3] = sWo; tp.dst[3] = wos;
  tp.src[4] = cWq; tp.dst[4] = wqc;
  tp.src[5] = cWk; tp.dst[5] = wkvc;
  tp.src[6] = cWv; tp.dst[6] = wkvc + DD;
  tp.src[7] = cWo; tp.dst[7] = woc;
  transpose_cvt8<<<dim3(32, 32, 8), 256, 0, stream>>>(tp);
  transpose_cvt<<<dim3(DF/32, D/32), 256, 0, stream>>>(fW1, wf1, D, DF);
  transpose_cvt<<<dim3(D/32, DF/32), 256, 0, stream>>>(fW2, wf2, DF, D);
  transpose_cvt<<<dim3(V/32, D/32), 256, 0, stream>>>(Wout, wvo, D, V);
  copy_biases<<<20, 256, 0, stream>>>(sbq, sbk, sbv, cbk, cbv, bqkv, bkvc);

  // 3. self-attention block
  gemm_bt<64,128,1><<<(M/64)*(3*D/128), 256, 0, stream>>>(x0b, wqkv, bqkv, qkv, M, 3*D, D);
  attn_kernel<1><<<dim3(S/64, 32), 256, 0, stream>>>(qkv, 3*D, qkv + D, 3*D, qkv + 2*D, 3*D, attnb, D);
  gemm_bt<64,64,0><<<(M/64)*(D/64), 256, 0, stream>>>(attnb, wos, sbo, oproj, M, D, D);
  ln_kernel<<<M, 256, 0, stream>>>(x0f, oproj, ln1g, ln1b, a1f, a1b);

  // 4. cross-attention block
  gemm_bt<64,64,1><<<(M/64)*(D/64), 256, 0, stream>>>(a1b, wqc, cbq, qc, M, D, D);
  gemm_bt<64,128,1><<<(M/64)*(2*D/128), 256, 0, stream>>>(encb, wkvc, bkvc, kvc, M, 2*D, D);
  attn_kernel<0><<<dim3(S/64, 32), 256, 0, stream>>>(qc, D, kvc, 2*D, kvc + D, 2*D, attnb, D);
  gemm_bt<64,64,0><<<(M/64)*(D/64), 256, 0, stream>>>(attnb, woc, cbo, oproj, M, D, D);
  ln_kernel<<<M, 256, 0, stream>>>(a1f, oproj, ln2g, ln2b, a2f, a2b);

  // 5. FFN (FFN1 on the 8-phase kernel; FFN2 on <64,128>)
  gemm256<2><<<(M/256)*(DF/256), 512, 0, stream>>>(a2b, wf1, fb1, ffh, M, DF, D);
  gemm_bt<64,128,0><<<(M/64)*(D/128), 256, 0, stream>>>(ffh, wf2, fb2, oproj, M, D, DF);
  ln_kernel<<<M, 256, 0, stream>>>(a2f, oproj, ln3g, ln3b, nullptr, yb);

  // 6. logits on the 8-phase kernel
  gemm256<3><<<(M/256)*(V/256), 512, 0, stream>>>(yb, wvo, bout, out, M, V, D);
}

// Round 4
// 641.407 us; speedup vs baseline: 1.0325x; 1.0325x over previous
//
#include <hip/hip_runtime.h>
#include <cstdint>
#include <cstddef>

#define DEV __device__ __forceinline__

typedef __attribute__((ext_vector_type(8))) short short8;
typedef __attribute__((ext_vector_type(4))) float f32x4;
typedef __attribute__((ext_vector_type(4))) unsigned short ushort4v;

DEV unsigned short f2bf(float f){
  union { float f; unsigned int i; } v; v.f = f;
  unsigned int r = v.i + 0x7fffu + ((v.i >> 16) & 1u);
  return (unsigned short)(r >> 16);
}

DEV void gld_lds16(const unsigned short* g, unsigned short* lds){
  __builtin_amdgcn_global_load_lds((const __attribute__((address_space(1))) void*)g,
                                   (__attribute__((address_space(3))) void*)lds, 16, 0, 0);
}

// =================== 256x256 8-wave deep-pipelined GEMM ===================
// C[M,N] = A[M,K] @ Bt[N,K]^T + bias.  BK=64, 4 phases/K-tile, ONE barrier/phase,
// counted vmcnt(4) once per tile (never 0 mid-loop). Compiler-managed lgkmcnt
// (fine-grained waits let MFMA start while later ds_reads drain; waves self-stagger).
// Region deadness: ph1 stages B{2,3}(u+1,pnx); ph2 A{1,3}(u+1,pnx); ph3 B{0,1}(u+2,pb)
// [B-nh0 last read in ph2]; ph4 A{0,2}(u+2,pb) [A-mh0 last read in ph3]. End-of-phase
// barrier guarantees all waves' reads of phase p landed (consumed by MFMA) before any
// wave's phase-p+1 stages overwrite. vmcnt(4) at tile end completes tile u+1 fully,
// leaves tile u+2's 4 chunks in flight.
template<int EPI>
__global__ __launch_bounds__(512, 2)
void gemm256(const unsigned short* __restrict__ A,
             const unsigned short* __restrict__ Bt,
             const float* __restrict__ bias,
             void* __restrict__ C, int M, int N, int K)
{
  __shared__ __align__(16) unsigned short lds[65536];   // 128 KiB

  const int tid = threadIdx.x, wid = tid >> 6, l = tid & 63;
  const int wr = wid >> 2, wc = wid & 3;

  const int nbm = M / 256, nbn = N / 256;
  const int nwg = nbm * nbn;
  const int q8 = nwg >> 3, r8 = nwg & 7;
  const int xcd = blockIdx.x & 7, within = blockIdx.x >> 3;
  const int wg = (xcd < r8 ? xcd * (q8 + 1) : r8 * (q8 + 1) + (xcd - r8) * q8) + within;
  const int mb = (wg % nbm) * 256, nb = (wg / nbm) * 256;

  const int nk = K / 64;   // must be even, >= 4

  const int srow8 = tid >> 3;
  const int sslot = (tid & 7) ^ ((tid >> 3) & 7);

  const int rl = l & 15, kslot = l >> 4, sx = l & 7;
  const int so0 = ((kslot) ^ sx) * 8;
  const int so1 = ((4 + kslot) ^ sx) * 8;
  const int arowb = wr * 128 + rl;
  const int bline = wc * 32 + rl;

  f32x4 acc[8][4];
  #pragma unroll
  for (int m = 0; m < 8; m++)
    #pragma unroll
    for (int n = 0; n < 4; n++) acc[m][n] = (f32x4){0.f, 0.f, 0.f, 0.f};

#define STAGE_A(c, tt, pp) \
  gld_lds16(A + (size_t)(mb + (c)*64 + srow8) * K + (size_t)(tt)*64 + sslot*8, \
            lds + (pp)*32768 + (c)*4096 + tid*8)
#define STAGE_B(c, tt, pp) \
  gld_lds16(Bt + (size_t)(nb + (((c)*2 + (srow8>>5)) & 3)*64 + ((c)>>1)*32 + (srow8&31)) * K \
                 + (size_t)(tt)*64 + sslot*8, \
            lds + (pp)*32768 + 16384 + (c)*4096 + tid*8)

#define PHASE(mh, nh, pb, STAGES, TAIL) do { \
    const unsigned short* lbase = lds + (pb)*32768; \
    short8 af[4][2], bf[2][2]; \
    _Pragma("unroll") \
    for (int i = 0; i < 4; i++){ \
      const unsigned short* ap = lbase + (arowb + (mh)*64 + i*16) * 64; \
      af[i][0] = *(const short8*)(ap + so0); \
      af[i][1] = *(const short8*)(ap + so1); \
    } \
    _Pragma("unroll") \
    for (int j = 0; j < 2; j++){ \
      const unsigned short* bp = lbase + 16384 + ((nh)*128 + bline + j*16) * 64; \
      bf[j][0] = *(const short8*)(bp + so0); \
      bf[j][1] = *(const short8*)(bp + so1); \
    } \
    STAGES; \
    __builtin_amdgcn_s_setprio(1); \
    _Pragma("unroll") \
    for (int i = 0; i < 4; i++) \
      _Pragma("unroll") \
      for (int j = 0; j < 2; j++){ \
        acc[(mh)*4+i][(nh)*2+j] = __builtin_amdgcn_mfma_f32_16x16x32_bf16(af[i][0], bf[j][0], acc[(mh)*4+i][(nh)*2+j], 0, 0, 0); \
        acc[(mh)*4+i][(nh)*2+j] = __builtin_amdgcn_mfma_f32_16x16x32_bf16(af[i][1], bf[j][1], acc[(mh)*4+i][(nh)*2+j], 0, 0, 0); \
      } \
    __builtin_amdgcn_s_setprio(0); \
    TAIL; \
    asm volatile("" ::: "memory"); \
    __builtin_amdgcn_s_barrier(); \
  } while(0)

#define TILE(pb, uu) do { \
    PHASE(0, 0, pb, { if ((uu) + 1 < nk){ STAGE_B(2, (uu)+1, (pb)^1); STAGE_B(3, (uu)+1, (pb)^1); } }, {}); \
    PHASE(1, 0, pb, { if ((uu) + 1 < nk){ STAGE_A(1, (uu)+1, (pb)^1); STAGE_A(3, (uu)+1, (pb)^1); } }, {}); \
    PHASE(0, 1, pb, { if ((uu) + 2 < nk){ STAGE_B(0, (uu)+2, (pb));   STAGE_B(1, (uu)+2, (pb));   } }, {}); \
    PHASE(1, 1, pb, { if ((uu) + 2 < nk){ STAGE_A(0, (uu)+2, (pb));   STAGE_A(2, (uu)+2, (pb));   } }, \
          { if ((uu) == nk - 2)     asm volatile("s_waitcnt vmcnt(0)" ::: "memory"); \
            else if ((uu) < nk - 2) asm volatile("s_waitcnt vmcnt(4)" ::: "memory"); }); \
  } while(0)

  // prologue: tile0 full -> buf0; tile1 chunks B0,B1,A0,A2 -> buf1
  STAGE_A(0, 0, 0); STAGE_A(1, 0, 0); STAGE_A(2, 0, 0); STAGE_A(3, 0, 0);
  STAGE_B(0, 0, 0); STAGE_B(1, 0, 0); STAGE_B(2, 0, 0); STAGE_B(3, 0, 0);
  if (nk > 1){ STAGE_B(0, 1, 1); STAGE_B(1, 1, 1); STAGE_A(0, 1, 1); STAGE_A(2, 1, 1); }
  if (nk > 1) asm volatile("s_waitcnt vmcnt(4)" ::: "memory");
  else        asm volatile("s_waitcnt vmcnt(0)" ::: "memory");
  asm volatile("" ::: "memory");
  __builtin_amdgcn_s_barrier();

  for (int u = 0; u < nk; u += 2){
    TILE(0, u);
    TILE(1, u + 1);
  }
#undef TILE
#undef PHASE
#undef STAGE_A
#undef STAGE_B

  // epilogue
  #pragma unroll
  for (int n = 0; n < 4; n++){
    const int col = nb + wc * 64 + n * 16 + rl;
    const float bv = bias ? bias[col] : 0.f;
    #pragma unroll
    for (int m = 0; m < 8; m++){
      const int row0 = mb + wr * 128 + m * 16 + (kslot << 2);
      #pragma unroll
      for (int jj = 0; jj < 4; jj++){
        float v = acc[m][n][jj] + bv;
        size_t idx = (size_t)(row0 + jj) * N + col;
        if (EPI == 0)       ((float*)C)[idx] = v;
        else if (EPI == 3)  __builtin_nontemporal_store(v, &((float*)C)[idx]);
        else if (EPI == 1)  ((unsigned short*)C)[idx] = f2bf(v);
        else { v = v > 0.f ? v : 0.f; ((unsigned short*)C)[idx] = f2bf(v); }
      }
    }
  }
}

// ---------------- GEMM (m97-style 2-phase): C[M,N] = A@Bt^T + bias ----------------
template<int BM, int BN, int EPI>
__global__ __launch_bounds__(256, 2)
void gemm_bt(const unsigned short* __restrict__ A,
             const unsigned short* __restrict__ Bt,
             const float* __restrict__ bias,
             void* __restrict__ C, int M, int N, int K)
{
  constexpr int MF = BM / 32, NF = BN / 32;
  constexpr int LA = BM / 64, LB = BN / 64;
  __shared__ __align__(16) unsigned short lds[2 * (BM + BN) * 32];

  const int tid = threadIdx.x, w = tid >> 6, l = tid & 63;
  const int wr = w >> 1, wc = w & 1;

  const int nbm = M / BM, nbn = N / BN;
  const int nwg = nbm * nbn;
  const int q8 = nwg >> 3, r8 = nwg & 7;
  const int xcd = blockIdx.x & 7, within = blockIdx.x >> 3;
  const int wg = (xcd < r8 ? xcd * (q8 + 1) : r8 * (q8 + 1) + (xcd - r8) * q8) + within;
  const int mb = (wg % nbm) * BM, nb = (wg / nbm) * BN;

  unsigned short* As0 = lds;
  unsigned short* Bs0 = lds + BM * 32;
  unsigned short* As1 = lds + (BM + BN) * 32;
  unsigned short* Bs1 = As1 + BM * 32;

  f32x4 acc[MF][NF];
  #pragma unroll
  for (int m = 0; m < MF; m++)
    #pragma unroll
    for (int n = 0; n < NF; n++) acc[m][n] = (f32x4){0.f, 0.f, 0.f, 0.f};

  const int srow = l >> 2;
  const int scol = (((l & 3) ^ ((l >> 2) & 3) ^ ((l >> 4) & 3)) * 8);
  const int rswz = (l & 3) ^ ((l >> 2) & 3);

  #define STAGE(Ad, Bd, k0) do { \
    _Pragma("unroll") \
    for (int i = 0; i < LA; i++){ \
      int chunk = i * 4 + w; \
      gld_lds16(A + (size_t)(mb + chunk * 16 + srow) * K + (k0) + scol, (Ad) + chunk * 512); \
    } \
    _Pragma("unroll") \
    for (int i = 0; i < LB; i++){ \
      int chunk = i * 4 + w; \
      gld_lds16(Bt + (size_t)(nb + chunk * 16 + srow) * K + (k0) + scol, (Bd) + chunk * 512); \
    } } while(0)

  STAGE(As0, Bs0, 0);
  const int nk = K / 32;
  const int rdoff = ((l >> 4) ^ rswz) * 8;
  for (int kt = 0; kt < nk; kt++){
    __syncthreads();
    unsigned short* Ac = (kt & 1) ? As1 : As0;
    unsigned short* Bc = (kt & 1) ? Bs1 : Bs0;
    if (kt + 1 < nk){
      unsigned short* An = (kt & 1) ? As0 : As1;
      unsigned short* Bn = (kt & 1) ? Bs0 : Bs1;
      STAGE(An, Bn, (kt + 1) * 32);
    }
    short8 af[MF], bfr[NF];
    #pragma unroll
    for (int m = 0; m < MF; m++)
      af[m] = *(const short8*)(Ac + (wr * (BM / 2) + m * 16 + (l & 15)) * 32 + rdoff);
    #pragma unroll
    for (int n = 0; n < NF; n++)
      bfr[n] = *(const short8*)(Bc + (wc * (BN / 2) + n * 16 + (l & 15)) * 32 + rdoff);
    #pragma unroll
    for (int m = 0; m < MF; m++)
      #pragma unroll
      for (int n = 0; n < NF; n++)
        acc[m][n] = __builtin_amdgcn_mfma_f32_16x16x32_bf16(af[m], bfr[n], acc[m][n], 0, 0, 0);
  }
  #undef STAGE

  #pragma unroll
  for (int n = 0; n < NF; n++){
    const int col = nb + wc * (BN / 2) + n * 16 + (l & 15);
    const float bv = bias ? bias[col] : 0.f;
    #pragma unroll
    for (int m = 0; m < MF; m++){
      const int row0 = mb + wr * (BM / 2) + m * 16 + ((l >> 4) << 2);
      #pragma unroll
      for (int jj = 0; jj < 4; jj++){
        float v = acc[m][n][jj] + bv;
        size_t idx = (size_t)(row0 + jj) * N + col;
        if (EPI == 0)       ((float*)C)[idx] = v;
        else if (EPI == 3)  __builtin_nontemporal_store(v, &((float*)C)[idx]);
        else if (EPI == 1)  ((unsigned short*)C)[idx] = f2bf(v);
        else { v = v > 0.f ? v : 0.f; ((unsigned short*)C)[idx] = f2bf(v); }
      }
    }
  }
}

// ---------------- Flash attention: 64 q-rows / block (4 waves x 16), dh=64, H=16 ----------------
template<int CAUSAL>
__global__ __launch_bounds__(256)
void attn_kernel(const unsigned short* __restrict__ Qb, int ldq,
                 const unsigned short* __restrict__ Kb, int ldk,
                 const unsigned short* __restrict__ Vb, int ldv,
                 unsigned short* __restrict__ Ob, int ldo)
{
  constexpr int S = 1024;
  __shared__ __align__(16) unsigned short vt[64][40];
  __shared__ __align__(16) unsigned short plds[4][16][40];
  const int tid = threadIdx.x, w = tid >> 6, l = tid & 63;
  const int qt = blockIdx.x, bh = blockIdx.y;
  const int b = bh >> 4, h = bh & 15;
  const int hoff = h * 64;
  const size_t rb = (size_t)b * S;

  const int qrow = qt * 64 + w * 16 + (l & 15);
  const unsigned short* qp = Qb + (rb + qrow) * ldq + hoff + ((l >> 4) * 8);
  short8 qf0 = *(const short8*)qp;
  short8 qf1 = *(const short8*)(qp + 32);

  float m_run[4] = {-1e30f, -1e30f, -1e30f, -1e30f};
  float l_run[4] = {0.f, 0.f, 0.f, 0.f};
  f32x4 oacc[4];
  #pragma unroll
  for (int t = 0; t < 4; t++) oacc[t] = (f32x4){0.f, 0.f, 0.f, 0.f};

  const int qmax = qt * 64 + w * 16 + 15;
  const int nkeys = CAUSAL ? (qt * 64 + 64) : S;
  const int skey = tid >> 3, sd8 = (tid & 7) * 8;

  for (int kb = 0; kb < nkeys; kb += 32){
    short8 vv = *(const short8*)(Vb + (rb + kb + skey) * ldv + hoff + sd8);
    #pragma unroll
    for (int i = 0; i < 8; i++) vt[sd8 + i][skey] = (unsigned short)vv[i];
    __syncthreads();
    if (!CAUSAL || kb <= qmax){
      f32x4 sc[2];
      #pragma unroll
      for (int g = 0; g < 2; g++){
        const unsigned short* kp = Kb + (rb + kb + g * 16 + (l & 15)) * ldk + hoff + ((l >> 4) * 8);
        short8 kf0 = *(const short8*)kp;
        short8 kf1 = *(const short8*)(kp + 32);
        f32x4 z = (f32x4){0.f, 0.f, 0.f, 0.f};
        z = __builtin_amdgcn_mfma_f32_16x16x32_bf16(qf0, kf0, z, 0, 0, 0);
        z = __builtin_amdgcn_mfma_f32_16x16x32_bf16(qf1, kf1, z, 0, 0, 0);
        sc[g] = z;
      }
      #pragma unroll
      for (int jj = 0; jj < 4; jj++){
        float s0 = sc[0][jj] * 0.125f, s1 = sc[1][jj] * 0.125f;
        if (CAUSAL){
          int q = qt * 64 + w * 16 + ((l >> 4) << 2) + jj;
          if (kb + (l & 15) > q)      s0 = -1e30f;
          if (kb + 16 + (l & 15) > q) s1 = -1e30f;
        }
        float mx = fmaxf(s0, s1);
        mx = fmaxf(mx, __shfl_xor(mx, 1));
        mx = fmaxf(mx, __shfl_xor(mx, 2));
        mx = fmaxf(mx, __shfl_xor(mx, 4));
        mx = fmaxf(mx, __shfl_xor(mx, 8));
        float mnew = fmaxf(m_run[jj], mx);
        float scal = __expf(m_run[jj] - mnew);
        m_run[jj] = mnew;
        float p0 = __expf(s0 - mnew), p1 = __expf(s1 - mnew);
        float rs = p0 + p1;
        rs += __shfl_xor(rs, 1); rs += __shfl_xor(rs, 2);
        rs += __shfl_xor(rs, 4); rs += __shfl_xor(rs, 8);
        l_run[jj] = l_run[jj] * scal + rs;
        #pragma unroll
        for (int t = 0; t < 4; t++) oacc[t][jj] *= scal;
        int qr = ((l >> 4) << 2) + jj;
        plds[w][qr][l & 15]      = f2bf(p0);
        plds[w][qr][16 + (l & 15)] = f2bf(p1);
      }
      asm volatile("s_waitcnt lgkmcnt(0)" ::: "memory");
      short8 pf = *(const short8*)&plds[w][l & 15][(l >> 4) * 8];
      #pragma unroll
      for (int t = 0; t < 4; t++){
        short8 vf = *(const short8*)&vt[t * 16 + (l & 15)][(l >> 4) * 8];
        oacc[t] = __builtin_amdgcn_mfma_f32_16x16x32_bf16(pf, vf, oacc[t], 0, 0, 0);
      }
    }
    __syncthreads();
  }
  #pragma unroll
  for (int jj = 0; jj < 4; jj++){
    float inv = 1.f / l_run[jj];
    int q = qt * 64 + w * 16 + ((l >> 4) << 2) + jj;
    #pragma unroll
    for (int t = 0; t < 4; t++)
      Ob[(rb + q) * ldo + hoff + t * 16 + (l & 15)] = f2bf(oacc[t][jj] * inv);
  }
}

// ---------------- LayerNorm over D=1024 ----------------
__global__ __launch_bounds__(256)
void ln_kernel(const float* __restrict__ x1, const float* __restrict__ x2,
               const float* __restrict__ g, const float* __restrict__ be,
               float* __restrict__ outf, unsigned short* __restrict__ outb)
{
  const int row = blockIdx.x, t = threadIdx.x;
  __shared__ float red[4];
  const float4 v1 = ((const float4*)(x1 + (size_t)row * 1024))[t];
  const float4 v2 = ((const float4*)(x2 + (size_t)row * 1024))[t];
  float x[4] = {v1.x + v2.x, v1.y + v2.y, v1.z + v2.z, v1.w + v2.w};
  float s = x[0] + x[1] + x[2] + x[3];
  for (int o = 1; o < 64; o <<= 1) s += __shfl_xor(s, o);
  const int w = t >> 6, l = t & 63;
  if (l == 0) red[w] = s;
  __syncthreads();
  const float mean = (red[0] + red[1] + red[2] + red[3]) * (1.f / 1024.f);
  float d[4]; float sq = 0.f;
  #pragma unroll
  for (int i = 0; i < 4; i++){ d[i] = x[i] - mean; sq += d[i] * d[i]; }
  __syncthreads();
  for (int o = 1; o < 64; o <<= 1) sq += __shfl_xor(sq, o);
  if (l == 0) red[w] = sq;
  __syncthreads();
  const float var = (red[0] + red[1] + red[2] + red[3]) * (1.f / 1024.f);
  const float inv = rsqrtf(var + 1e-5f);
  const int base = t * 4;
  #pragma unroll
  for (int i = 0; i < 4; i++){
    float o = d[i] * inv * g[base + i] + be[base + i];
    if (outf) outf[(size_t)row * 1024 + base + i] = o;
    outb[(size_t)row * 1024 + base + i] = f2bf(o);
  }
}

// ---------------- x0 = dec + positional encoding ----------------
__global__ __launch_bounds__(256)
void build_x0(const float* __restrict__ dec, float* __restrict__ xf, unsigned short* __restrict__ xb)
{
  const int i = blockIdx.x * 256 + threadIdx.x;
  const int i4 = i * 4;
  const int d0 = i4 & 1023;
  const int s  = (i4 >> 10) & 1023;
  float4 dv = ((const float4*)dec)[i];
  const float* dvp = (const float*)&dv;
  float o[4];
  #pragma unroll
  for (int j = 0; j < 4; j++){
    int dd = d0 + j;
    float e = (float)(dd & ~1) * (1.f / 1024.f);
    float den = expf(e * 9.210340371976184f);
    float ang = (float)s / den;
    float pe = (dd & 1) ? cosf(ang) : sinf(ang);
    o[j] = dvp[j] + pe;
  }
  ((float4*)xf)[i] = make_float4(o[0], o[1], o[2], o[3]);
  ushort4v ob; ob[0] = f2bf(o[0]); ob[1] = f2bf(o[1]); ob[2] = f2bf(o[2]); ob[3] = f2bf(o[3]);
  ((ushort4v*)xb)[i] = ob;
}

__global__ __launch_bounds__(256)
void cvt_bf16_k(const float* __restrict__ in, unsigned short* __restrict__ out)
{
  const int i = blockIdx.x * 256 + threadIdx.x;
  float4 v = ((const float4*)in)[i];
  ushort4v o; o[0] = f2bf(v.x); o[1] = f2bf(v.y); o[2] = f2bf(v.z); o[3] = f2bf(v.w);
  ((ushort4v*)out)[i] = o;
}

// ---------------- transpose + convert ----------------
__global__ __launch_bounds__(256)
void transpose_cvt(const float* __restrict__ in, unsigned short* __restrict__ out, int R, int C)
{
  __shared__ float t[32][33];
  const int cb = blockIdx.x * 32, rbk = blockIdx.y * 32;
  const int tx = threadIdx.x & 31, ty = threadIdx.x >> 5;
  #pragma unroll
  for (int i = 0; i < 4; i++)
    t[ty + 8 * i][tx] = in[(size_t)(rbk + ty + 8 * i) * C + cb + tx];
  __syncthreads();
  #pragma unroll
  for (int i = 0; i < 4; i++){
    int c = ty + 8 * i;
    out[(size_t)(cb + c) * R + rbk + tx] = f2bf(t[tx][c]);
  }
}

struct TPtrs { const float* src[8]; unsigned short* dst[8]; };
__global__ __launch_bounds__(256)
void transpose_cvt8(TPtrs p)
{
  __shared__ float t[32][33];
  const float* __restrict__ in = p.src[blockIdx.z];
  unsigned short* __restrict__ out = p.dst[blockIdx.z];
  const int cb = blockIdx.x * 32, rbk = blockIdx.y * 32;
  const int tx = threadIdx.x & 31, ty = threadIdx.x >> 5;
  #pragma unroll
  for (int i = 0; i < 4; i++)
    t[ty + 8 * i][tx] = in[(size_t)(rbk + ty + 8 * i) * 1024 + cb + tx];
  __syncthreads();
  #pragma unroll
  for (int i = 0; i < 4; i++){
    int c = ty + 8 * i;
    out[(size_t)(cb + c) * 1024 + rbk + tx] = f2bf(t[tx][c]);
  }
}

__global__ __launch_bounds__(256)
void copy_biases(const float* sbq, const float* sbk, const float* sbv,
                 const float* cbk, const float* cbv,
                 float* bqkv, float* bkvc)
{
  const int i = blockIdx.x * 256 + threadIdx.x;
  const int seg = i >> 10, off = i & 1023;
  if (seg == 0)      bqkv[off] = sbq[off];
  else if (seg == 1) bqkv[1024 + off] = sbk[off];
  else if (seg == 2) bqkv[2048 + off] = sbv[off];
  else if (seg == 3) bkvc[off] = cbk[off];
  else               bkvc[1024 + off] = cbv[off];
}

extern "C" void kernel_launch(void* const* d_in, const int* in_sizes, int n_in,
                              void* d_out, int out_size, void* d_ws, size_t ws_size,
                              hipStream_t stream)
{
  constexpr int S = 1024, D = 1024, V = 32000, DF = 4096;
  constexpr int M = 2 * S;
  constexpr int DD = D * D;
  constexpr int l3 = 3;

  const float* dec  = (const float*)d_in[0];
  const float* enc  = (const float*)d_in[1];
  const float* sWq = (const float*)d_in[5]  + l3 * DD;
  const float* sWk = (const float*)d_in[6]  + l3 * DD;
  const float* sWv = (const float*)d_in[7]  + l3 * DD;
  const float* sWo = (const float*)d_in[8]  + l3 * DD;
  const float* cWq = (const float*)d_in[9]  + l3 * DD;
  const float* cWk = (const float*)d_in[10] + l3 * DD;
  const float* cWv = (const float*)d_in[11] + l3 * DD;
  const float* cWo = (const float*)d_in[12] + l3 * DD;
  const float* sbq = (const float*)d_in[13] + l3 * D;
  const float* sbk = (const float*)d_in[14] + l3 * D;
  const float* sbv = (const float*)d_in[15] + l3 * D;
  const float* sbo = (const float*)d_in[16] + l3 * D;
  const float* cbq = (const float*)d_in[17] + l3 * D;
  const float* cbk = (const float*)d_in[18] + l3 * D;
  const float* cbv = (const float*)d_in[19] + l3 * D;
  const float* cbo = (const float*)d_in[20] + l3 * D;
  const float* ln1g = (const float*)d_in[21] + l3 * D;
  const float* ln2g = (const float*)d_in[22] + l3 * D;
  const float* ln3g = (const float*)d_in[23] + l3 * D;
  const float* ln1b = (const float*)d_in[24] + l3 * D;
  const float* ln2b = (const float*)d_in[25] + l3 * D;
  const float* ln3b = (const float*)d_in[26] + l3 * D;
  const float* fW1 = (const float*)d_in[27] + (size_t)l3 * D * DF;
  const float* fb1 = (const float*)d_in[28] + l3 * DF;
  const float* fW2 = (const float*)d_in[29] + (size_t)l3 * DF * D;
  const float* fb2 = (const float*)d_in[30] + l3 * D;
  const float* Wout = (const float*)d_in[31];
  const float* bout = (const float*)d_in[32];
  float* out = (float*)d_out;

  uint8_t* wsp = (uint8_t*)d_ws;
  auto alloc = [&](size_t bytes) -> void* {
    void* p = wsp; wsp += (bytes + 255) & ~(size_t)255; return p;
  };
  float*          x0f  = (float*)alloc((size_t)M * D * 4);
  unsigned short* x0b  = (unsigned short*)alloc((size_t)M * D * 2);
  unsigned short* encb = (unsigned short*)alloc((size_t)M * D * 2);
  unsigned short* wqkv = (unsigned short*)alloc((size_t)3 * DD * 2);
  unsigned short* wos  = (unsigned short*)alloc((size_t)DD * 2);
  unsigned short* wqc  = (unsigned short*)alloc((size_t)DD * 2);
  unsigned short* wkvc = (unsigned short*)alloc((size_t)2 * DD * 2);
  unsigned short* woc  = (unsigned short*)alloc((size_t)DD * 2);
  unsigned short* wf1  = (unsigned short*)alloc((size_t)D * DF * 2);
  unsigned short* wf2  = (unsigned short*)alloc((size_t)D * DF * 2);
  unsigned short* wvo  = (unsigned short*)alloc((size_t)V * D * 2);
  float*          bqkv = (float*)alloc(3 * D * 4);
  float*          bkvc = (float*)alloc(2 * D * 4);
  unsigned short* qkv  = (unsigned short*)alloc((size_t)M * 3 * D * 2);
  unsigned short* attnb= (unsigned short*)alloc((size_t)M * D * 2);
  float*          oproj= (float*)alloc((size_t)M * D * 4);
  float*          a1f  = (float*)alloc((size_t)M * D * 4);
  unsigned short* a1b  = (unsigned short*)alloc((size_t)M * D * 2);
  unsigned short* qc   = (unsigned short*)alloc((size_t)M * D * 2);
  unsigned short* kvc  = (unsigned short*)alloc((size_t)M * 2 * D * 2);
  float*          a2f  = (float*)alloc((size_t)M * D * 4);
  unsigned short* a2b  = (unsigned short*)alloc((size_t)M * D * 2);
  unsigned short* ffh  = (unsigned short*)alloc((size_t)M * DF * 2);
  unsigned short* yb   = (unsigned short*)alloc((size_t)M * D * 2);

  build_x0<<<M * D / 4 / 256, 256, 0, stream>>>(dec, x0f, x0b);
  cvt_bf16_k<<<M * D / 4 / 256, 256, 0, stream>>>(enc, encb);

  TPtrs tp;
  tp.src[0] = sWq; tp.dst[0] = wqkv;
  tp.src[1] = sWk; tp.dst[1] = wqkv + DD;
  tp.src[2] = sWv; tp.dst[2] = wqkv + 2 * DD;
  tp.src[3] = sWo; tp.dst[3] = wos;
  tp.src[4] = cWq; tp.dst[4] = wqc;
  tp.src[5] = cWk; tp.dst[5] = wkvc;
  tp.src[6] = cWv; tp.dst[6] = wkvc + DD;
  tp.src[7] = cWo; tp.dst[7] = woc;
  transpose_cvt8<<<dim3(32, 32, 8), 256, 0, stream>>>(tp);
  transpose_cvt<<<dim3(DF/32, D/32), 256, 0, stream>>>(fW1, wf1, D, DF);
  transpose_cvt<<<dim3(D/32, DF/32), 256, 0, stream>>>(fW2, wf2, DF, D);
  transpose_cvt<<<dim3(V/32, D/32), 256, 0, stream>>>(Wout, wvo, D, V);
  copy_biases<<<20, 256, 0, stream>>>(sbq, sbk, sbv, cbk, cbv, bqkv, bkvc);

  // 3. self-attention block
  gemm_bt<64,128,1><<<(M/64)*(3*D/128), 256, 0, stream>>>(x0b, wqkv, bqkv, qkv, M, 3*D, D);
  attn_kernel<1><<<dim3(S/64, 32), 256, 0, stream>>>(qkv, 3*D, qkv + D, 3*D, qkv + 2*D, 3*D, attnb, D);
  gemm_bt<64,64,0><<<(M/64)*(D/64), 256, 0, stream>>>(attnb, wos, sbo, oproj, M, D, D);
  ln_kernel<<<M, 256, 0, stream>>>(x0f, oproj, ln1g, ln1b, a1f, a1b);

  // 4. cross-attention block
  gemm_bt<64,64,1><<<(M/64)*(D/64), 256, 0, stream>>>(a1b, wqc, cbq, qc, M, D, D);
  gemm_bt<64,128,1><<<(M/64)*(2*D/128), 256, 0, stream>>>(encb, wkvc, bkvc, kvc, M, 2*D, D);
  attn_kernel<0><<<dim3(S/64, 32), 256, 0, stream>>>(qc, D, kvc, 2*D, kvc + D, 2*D, attnb, D);
  gemm_bt<64,64,0><<<(M/64)*(D/64), 256, 0, stream>>>(attnb, woc, cbo, oproj, M, D, D);
  ln_kernel<<<M, 256, 0, stream>>>(a1f, oproj, ln2g, ln2b, a2f, a2b);

  // 5. FFN (FFN1 back to 2-phase 128x128: grid 512 fills all CUs)
  gemm_bt<128,128,2><<<(M/128)*(DF/128), 256, 0, stream>>>(a2b, wf1, fb1, ffh, M, DF, D);
  gemm_bt<64,128,0><<<(M/64)*(D/128), 256, 0, stream>>>(ffh, wf2, fb2, oproj, M, D, DF);
  ln_kernel<<<M, 256, 0, stream>>>(a2f, oproj, ln3g, ln3b, nullptr, yb);

  // 6. logits on the single-barrier 8-phase kernel
  gemm256<3><<<(M/256)*(V/256), 512, 0, stream>>>(yb, wvo, bout, out, M, V, D);
}